// Round 8
// baseline (211.037 us; speedup 1.0000x reference)
//
#include <hip/hip_runtime.h>
#include <math.h>

#define NROWS 16384
#define INDIM 2048
#define NE 16
#define RPB 32                    // rows per block (8 waves x 4 rows)
#define RPW 4                     // rows per wave
#define NWAVE 8
#define SEG 256                   // floats per k-segment (64 lanes x float4)
#define NSEG 8

// Structure rationale (R3-R7 evidence): every loop-resident global-load scheme
// plateaued at 60-80us with VALU-busy ~18us constant -> per-chunk exposed
// latency, compiler merges vmcnt waits. Fix: NO VMEM in main loop. Full W1
// (128KB) lives in LDS (staged once); x lives in registers (two 64-reg
// phases). 1 block/CU (LDS-bound), 8 waves = 2/SIMD.
__global__ __launch_bounds__(512, 2) void gate_kernel(
    const float* __restrict__ x,
    const float* __restrict__ W1,
    const float* __restrict__ W2,
    float* __restrict__ out)
{
    __shared__ float w1s[NE * INDIM];    // 131072 B — full W1, row-major copy
    __shared__ float hbuf[RPB][17];
    __shared__ float w2s[NE * NE];

    const int tid  = threadIdx.x;
    const int lane = tid & 63;
    const int wv   = tid >> 6;                        // 0..7
    const int row0 = blockIdx.x * RPB;
    const int rowW = row0 + wv * RPW;

    const float* xw = x + (size_t)rowW * INDIM + lane * 4;

    // ---- issue x phase-A loads first (16 float4/thread, coalesced 1KB/inst) ----
    float4 xr[RPW][4];
    #pragma unroll
    for (int r = 0; r < RPW; ++r)
        #pragma unroll
        for (int s = 0; s < 4; ++s)
            xr[r][s] = *(const float4*)(xw + (size_t)r * INDIM + s * SEG);

    // ---- stage full W1 -> LDS (16 float4/thread; ds_write vmcnt wait absorbs
    //      the x-load latency issued above) ----
    {
        float4 g[16];
        #pragma unroll
        for (int i = 0; i < 16; ++i)
            g[i] = ((const float4*)W1)[i * 512 + tid];
        #pragma unroll
        for (int i = 0; i < 16; ++i)
            ((float4*)w1s)[i * 512 + tid] = g[i];
    }
    if (tid < 64) ((float4*)w2s)[tid] = ((const float4*)W2)[tid];

    float acc[RPW * NE];
    #pragma unroll
    for (int i = 0; i < RPW * NE; ++i) acc[i] = 0.0f;

    __syncthreads();   // W1 + w2s visible; x regs ready (drained by ds_writes)

    // ---- main loop phase A: s=0..3 — pure VALU + LDS, no barriers, no VMEM ----
    #pragma unroll
    for (int s = 0; s < 4; ++s) {
        #pragma unroll
        for (int e = 0; e < NE; ++e) {
            const float4 wq = *(const float4*)&w1s[e * INDIM + s * SEG + lane * 4];
            #pragma unroll
            for (int r = 0; r < RPW; ++r) {
                float a = acc[r * NE + e];
                a = fmaf(xr[r][s].x, wq.x, a);
                a = fmaf(xr[r][s].y, wq.y, a);
                a = fmaf(xr[r][s].z, wq.z, a);
                a = fmaf(xr[r][s].w, wq.w, a);
                acc[r * NE + e] = a;
            }
        }
    }

    // ---- reload x regs for phase B (one-time ~HBM-latency bubble, covered by
    //      the co-resident wave on each SIMD) ----
    #pragma unroll
    for (int r = 0; r < RPW; ++r)
        #pragma unroll
        for (int s = 0; s < 4; ++s)
            xr[r][s] = *(const float4*)(xw + (size_t)r * INDIM + (s + 4) * SEG);

    #pragma unroll
    for (int s = 0; s < 4; ++s) {
        #pragma unroll
        for (int e = 0; e < NE; ++e) {
            const float4 wq = *(const float4*)&w1s[e * INDIM + (s + 4) * SEG + lane * 4];
            #pragma unroll
            for (int r = 0; r < RPW; ++r) {
                float a = acc[r * NE + e];
                a = fmaf(xr[r][s].x, wq.x, a);
                a = fmaf(xr[r][s].y, wq.y, a);
                a = fmaf(xr[r][s].z, wq.z, a);
                a = fmaf(xr[r][s].w, wq.w, a);
                acc[r * NE + e] = a;
            }
        }
    }

    // ---- folding butterfly: 64 lane-partials -> full sums in 63 shuffles ----
    #pragma unroll
    for (int s = 0; s < 6; ++s) {
        const int m = 1 << s;
        const int h = 32 >> s;
        const int b = (lane >> s) & 1;
        #pragma unroll
        for (int i = 0; i < h; ++i) {
            const float keep = b ? acc[i + h] : acc[i];
            const float send = b ? acc[i] : acc[i + h];
            acc[i] = keep + __shfl_xor(send, m, 64);
        }
    }
    {
        int v = 0;
        #pragma unroll
        for (int s = 0; s < 6; ++s) v |= ((lane >> s) & 1) << (5 - s);
        hbuf[wv * RPW + (v >> 4)][v & 15] = tanhf(acc[0]);
    }
    __syncthreads();

    // ---- per-row tail: logits, sort, softmax, k policy, outputs ----
    if (tid < RPB) {
        const int r   = tid;
        const int row = row0 + r;

        float hr[NE];
        #pragma unroll
        for (int e = 0; e < NE; ++e) hr[e] = hbuf[r][e];

        float v[NE];
        int   idx[NE];
        #pragma unroll
        for (int f = 0; f < NE; ++f) {
            float s = 0.0f;
            #pragma unroll
            for (int j = 0; j < 4; ++j) {
                const float4 w = ((const float4*)w2s)[f * 4 + j];
                s = fmaf(hr[4 * j + 0], w.x, s);
                s = fmaf(hr[4 * j + 1], w.y, s);
                s = fmaf(hr[4 * j + 2], w.z, s);
                s = fmaf(hr[4 * j + 3], w.w, s);
            }
            v[f]   = s / 0.7f;
            idx[f] = f;
        }

        // bitonic sort on key (-value, index): stable descending argsort
        #pragma unroll
        for (int ksz = 2; ksz <= 16; ksz <<= 1) {
            #pragma unroll
            for (int jsz = ksz >> 1; jsz >= 1; jsz >>= 1) {
                #pragma unroll
                for (int i = 0; i < 16; ++i) {
                    const int l = i ^ jsz;
                    if (l > i) {
                        const bool asc   = ((i & ksz) == 0);
                        const bool keyGt = (v[i] < v[l]) ||
                                           (v[i] == v[l] && idx[i] > idx[l]);
                        if (keyGt == asc) {
                            float tv = v[i]; v[i] = v[l]; v[l] = tv;
                            int   ti = idx[i]; idx[i] = idx[l]; idx[l] = ti;
                        }
                    }
                }
            }
        }

        float p[NE];
        float tot = 0.0f;
        #pragma unroll
        for (int i = 0; i < NE; ++i) { p[i] = expf(v[i] - v[0]); tot += p[i]; }
        #pragma unroll
        for (int i = 0; i < NE; ++i) p[i] = p[i] / tot;

        float cum[NE];
        cum[0] = p[0];
        #pragma unroll
        for (int i = 1; i < NE; ++i) cum[i] = cum[i - 1] + p[i];

        int k = NE;
        #pragma unroll
        for (int i = NE - 1; i >= 0; --i) if (cum[i] >= 0.92f) k = i + 1;

        if ((p[0] >= 0.46f) && ((p[0] - p[1]) >= 0.1f)) k = 1;
        if ((k > 2) && ((cum[1] >= 0.82f) || (p[2] <= 0.12f) || ((p[1] - p[2]) <= 0.03f)))
            k = 2;
        k = k < 1 ? 1 : (k > 3 ? 3 : k);

        const float4 o0 = make_float4((float)idx[0], (float)idx[1], (float)idx[2], (float)idx[3]);
        const float4 o1 = make_float4((float)idx[4], (float)idx[5], (float)idx[6], (float)idx[7]);
        const float4 s0 = make_float4(k > 0 ? p[0] : 0.0f, k > 1 ? p[1] : 0.0f,
                                      k > 2 ? p[2] : 0.0f, k > 3 ? p[3] : 0.0f);
        const float4 s1 = make_float4(k > 4 ? p[4] : 0.0f, k > 5 ? p[5] : 0.0f,
                                      k > 6 ? p[6] : 0.0f, k > 7 ? p[7] : 0.0f);
        const float4 m0 = make_float4(k > 0 ? 1.0f : 0.0f, k > 1 ? 1.0f : 0.0f,
                                      k > 2 ? 1.0f : 0.0f, k > 3 ? 1.0f : 0.0f);
        const float4 m1 = make_float4(k > 4 ? 1.0f : 0.0f, k > 5 ? 1.0f : 0.0f,
                                      k > 6 ? 1.0f : 0.0f, k > 7 ? 1.0f : 0.0f);

        float4* oI = (float4*)(out + (size_t)row * 8);
        float4* oS = (float4*)(out + (size_t)NROWS * 8  + (size_t)row * 8);
        float4* oM = (float4*)(out + (size_t)NROWS * 16 + (size_t)row * 8);
        oI[0] = o0; oI[1] = o1;
        oS[0] = s0; oS[1] = s1;
        oM[0] = m0; oM[1] = m1;
        out[(size_t)NROWS * 24 + row] = (float)k;
    }
}

extern "C" void kernel_launch(void* const* d_in, const int* in_sizes, int n_in,
                              void* d_out, int out_size, void* d_ws, size_t ws_size,
                              hipStream_t stream)
{
    const float* x  = (const float*)d_in[0];
    const float* W1 = (const float*)d_in[1];
    const float* W2 = (const float*)d_in[2];
    gate_kernel<<<NROWS / RPB, 512, 0, stream>>>(x, W1, W2, (float*)d_out);
}